// Round 6
// baseline (800.827 us; speedup 1.0000x reference)
//
#include <hip/hip_runtime.h>
#include <cstdint>
#include <cstddef>

// Problem constants. Inputs/outputs fp32 (confirmed R4).
#define B_     4
#define N_     4096
#define C_     768
#define HEADS_ 12
#define PTS_   4
#define HD_    64
#define HID_   3072
#define HH_    64
#define WW_    64

typedef unsigned short u16;
typedef unsigned int   u32;
typedef __bf16 bf16x8 __attribute__((ext_vector_type(8)));
typedef float  f32x4  __attribute__((ext_vector_type(4)));
typedef unsigned short ushort8 __attribute__((ext_vector_type(8)));

__device__ __forceinline__ float b2f(u16 x) {
    union { unsigned int u; float f; } v; v.u = ((unsigned int)x) << 16; return v.f;
}
__device__ __forceinline__ u16 f2bf(float f) {
    union { float f; unsigned int u; } v; v.f = f;
    unsigned int u = v.u;
    u = u + 0x7fffu + ((u >> 16) & 1u);   // RNE
    return (u16)(u >> 16);
}
__device__ __forceinline__ int   ui(int x)   { return __builtin_amdgcn_readfirstlane(x); }
__device__ __forceinline__ float uf(float x) { return __int_as_float(__builtin_amdgcn_readfirstlane(__float_as_int(x))); }

// async global->LDS, 16B/lane; LDS dst wave-uniform base, lane i -> base+i*16.
__device__ __forceinline__ void gl16(const u16* g, u16* l) {
    __builtin_amdgcn_global_load_lds((const __attribute__((address_space(1))) void*)g,
                                     (__attribute__((address_space(3))) void*)l, 16, 0, 0);
}

// ---------------------------------------------------------------------------
// fp32 weights/biases -> bf16 workspace.
// ---------------------------------------------------------------------------
__global__ __launch_bounds__(256) void convert_k(
    const float* qkvw, const float* projw, const float* fc1w, const float* fc2w,
    const float* offw, const float* qkvb, const float* projb, const float* fc1b,
    const float* fc2b, const float* offb, const float* n1w, const float* n1b,
    const float* n2w, const float* n2b,
    u16* __restrict__ dst)
{
    const int total = 7161696;
    for (int i = (int)blockIdx.x * 256 + (int)threadIdx.x; i < total; i += (int)gridDim.x * 256) {
        const float* src; int off;
        if      (i < 1769472) { src = qkvw;  off = i; }
        else if (i < 2359296) { src = projw; off = i - 1769472; }
        else if (i < 4718592) { src = fc1w;  off = i - 2359296; }
        else if (i < 7077888) { src = fc2w;  off = i - 4718592; }
        else if (i < 7151616) { src = offw;  off = i - 7077888; }
        else if (i < 7153920) { src = qkvb;  off = i - 7151616; }
        else if (i < 7154688) { src = projb; off = i - 7153920; }
        else if (i < 7157760) { src = fc1b;  off = i - 7154688; }
        else if (i < 7158528) { src = fc2b;  off = i - 7157760; }
        else if (i < 7158624) { src = offb;  off = i - 7158528; }
        else if (i < 7159392) { src = n1w;   off = i - 7158624; }
        else if (i < 7160160) { src = n1b;   off = i - 7159392; }
        else if (i < 7160928) { src = n2w;   off = i - 7160160; }
        else                  { src = n2b;   off = i - 7160928; }
        dst[i] = f2bf(src[off]);
    }
}

// ---------------------------------------------------------------------------
// OLD GEMM (128x128x64, 2-barrier). Kept for the tiny off-GEMM (N=96 row
// clamping).
// ---------------------------------------------------------------------------
#define BM 128
#define BN 128
#define BK 64

template <int EPI, typename TRES, typename TOUT>
__global__ __launch_bounds__(256) void gemm_nt(
    const u16* __restrict__ A, int lda,
    const u16* __restrict__ Bw,
    const u16* __restrict__ bias,
    const void* __restrict__ resid,
    void* __restrict__ outv,
    int M, int N, int K)
{
    __shared__ alignas(16) u16 As[BM * BK];   // 16 KB
    __shared__ alignas(16) u16 Bs[BN * BK];   // 16 KB

    const int tid  = (int)threadIdx.x;
    const int wid  = tid >> 6;
    const int lane = tid & 63;
    const int l15  = lane & 15;
    const int quad = lane >> 4;
    const int m0   = (int)blockIdx.y * BM;
    const int n0   = (int)blockIdx.x * BN;
    const int wm   = (wid & 1) * 64;
    const int wn   = (wid >> 1) * 64;

    const f32x4 zero4 = {0.f, 0.f, 0.f, 0.f};
    f32x4 acc[4][4];
#pragma unroll
    for (int i = 0; i < 4; i++)
#pragma unroll
        for (int j = 0; j < 4; j++) acc[i][j] = zero4;

    const int srow = tid >> 3;                         // 0..31
    const int scol = (((tid & 7) ^ (srow & 7))) * 8;   // swizzled source col (u16)
    const u16* pa = A + (size_t)(m0 + srow) * lda + scol;
    int brow[4];
#pragma unroll
    for (int q = 0; q < 4; q++) {
        int r = n0 + srow + q * 32;
        brow[q] = (r > N - 1) ? (N - 1) : r;
    }

    const int swz = l15 & 7;  // fragment-row & 7, lane-constant

    for (int k0 = 0; k0 < K; k0 += BK) {
        __syncthreads();
#pragma unroll
        for (int q = 0; q < 4; q++) {
            gl16(pa + (size_t)(q * 32) * lda + k0, As + (size_t)(q * 256 + wid * 64) * 8);
            gl16(Bw + (size_t)brow[q] * K + scol + k0, Bs + (size_t)(q * 256 + wid * 64) * 8);
        }
        __syncthreads();

#pragma unroll
        for (int half = 0; half < 2; half++) {
            bf16x8 af[4], bfr[4];
#pragma unroll
            for (int i = 0; i < 4; i++)
                af[i] = *(const bf16x8*)(As + (wm + i * 16 + l15) * BK + (((half * 4 + quad) ^ swz) * 8));
#pragma unroll
            for (int j = 0; j < 4; j++)
                bfr[j] = *(const bf16x8*)(Bs + (wn + j * 16 + l15) * BK + (((half * 4 + quad) ^ swz) * 8));
#pragma unroll
            for (int i = 0; i < 4; i++)
#pragma unroll
                for (int j = 0; j < 4; j++)
                    acc[i][j] = __builtin_amdgcn_mfma_f32_16x16x32_bf16(af[i], bfr[j], acc[i][j], 0, 0, 0);
        }
    }

#pragma unroll
    for (int j = 0; j < 4; j++) {
        int ncol = n0 + wn + j * 16 + l15;
        if (ncol >= N) continue;
        float bb = b2f(bias[ncol]);
#pragma unroll
        for (int i = 0; i < 4; i++) {
            int mbase = m0 + wm + i * 16 + quad * 4;
#pragma unroll
            for (int r = 0; r < 4; r++) {
                int m = mbase + r;
                float v = acc[i][j][r] + bb;
                if (EPI == 0) {
                    ((u16*)outv)[(size_t)m * N + ncol] = f2bf(v);
                } else if (EPI == 1) {
                    float g = 0.5f * v * (1.0f + erff(v * 0.70710678118654752f));
                    ((u16*)outv)[(size_t)m * N + ncol] = f2bf(g);
                } else if (EPI == 2) {
                    size_t idx = (size_t)m * N + ncol;
                    float res = (sizeof(TRES) == 4) ? ((const float*)resid)[idx]
                                                    : b2f(((const u16*)resid)[idx]);
                    float o = v + res;
                    if (sizeof(TOUT) == 4) ((float*)outv)[idx] = o;
                    else                   ((u16*)outv)[idx]   = f2bf(o);
                } else {
                    int oc = (ncol < 768) ? ncol
                           : (ncol < 1536) ? (768 + ((ncol - 768) << 1))
                                           : (768 + ((ncol - 1536) << 1) + 1);
                    ((u16*)outv)[(size_t)m * 2304 + oc] = f2bf(v);
                }
            }
        }
    }
}

// ---------------------------------------------------------------------------
// gemm1b: 256x256 tile, BK=32, SINGLE 32 KB LDS buffer, 512 threads (8 waves,
// 2M x 4N, per-wave C = 128x64), plain 2-barrier loop -> 4 co-resident
// blocks/CU (LDS 4x32=128<=160 KB, 32 waves).  The DMA stall at each
// barrier-drain is absorbed by the other 3 blocks' streams (m97 mechanism,
// measured 13.4 TB/s staging at 3 streams) at 2x the FLOP/byte of 128^2.
//
// LDS layout: row r (64 B) x 4 granules of 16 B; slot (r, q) holds source
// granule q ^ (r&3) (XOR swizzle; read side XORs by l15&3; bank-uniform).
// Staging: thread t covers slot G=t and G=512+t (rows +128); gl16 dst is
// wave-uniform (wid*1024 B).  Fragment/epilogue math identical to the
// verified gemm8 (R3/R5).  Requires M%256==0, N%256==0, K%32==0, grid%8==0.
// ---------------------------------------------------------------------------
template <int EPI, typename TRES, typename TOUT>
__global__ __launch_bounds__(512) void gemm1b(
    const u16* __restrict__ A, int lda,
    const u16* __restrict__ Bw,
    const u16* __restrict__ bias,
    const void* __restrict__ resid,
    void* __restrict__ outv,
    int M, int N, int K)
{
    __shared__ alignas(16) u16 As[256 * 32];   // 16 KB
    __shared__ alignas(16) u16 Bs[256 * 32];   // 16 KB

    const int tid  = (int)threadIdx.x;
    const int wid  = tid >> 6;
    const int lane = tid & 63;
    const int l15  = lane & 15;
    const int quad = lane >> 4;
    const int wave_m = wid & 1;
    const int wave_n = wid >> 1;

    // bijective XCD swizzle (all call sites have nwg % 8 == 0)
    const int gx  = (int)gridDim.x;
    const int nwg = gx * (int)gridDim.y;
    const int lin = (int)blockIdx.y * gx + (int)blockIdx.x;
    const int swzb = (lin & 7) * (nwg >> 3) + (lin >> 3);
    const int m0 = (swzb / gx) * 256;
    const int n0 = (swzb % gx) * 256;

    const f32x4 zero4 = {0.f, 0.f, 0.f, 0.f};
    f32x4 acc[8][4];
#pragma unroll
    for (int i = 0; i < 8; i++)
#pragma unroll
        for (int j = 0; j < 4; j++) acc[i][j] = zero4;

    // staging: thread t -> slot row rt=t>>2 (0..127), slot granule t&3;
    // source granule (t&3)^(rt&3).  Call 2: rows +128 (row&3 unchanged).
    const int rt = tid >> 2;
    const int gs = (tid & 3) ^ (rt & 3);
    const u16* pA = A  + (size_t)(m0 + rt) * lda + gs * 8;
    const u16* pB = Bw + (size_t)(n0 + rt) * K   + gs * 8;
    const size_t a128 = (size_t)128 * lda;
    const size_t b128 = (size_t)128 * K;
    u16* const dA = As + wid * 512;            // wave-uniform LDS dst (u16)
    u16* const dB = Bs + wid * 512;

    // fragment-read constants: row = wave_*... + i*16 + l15 (row&3 == l15&3);
    // k-granule quad stored at slot granule quad ^ (l15&3).
    const int kg  = (quad ^ (l15 & 3)) * 8;
    const int aoff = (wave_m * 128 + l15) * 32 + kg;
    const int boff = (wave_n * 64  + l15) * 32 + kg;

    const int nt = K >> 5;

    for (int t = 0; t < nt; ++t) {
        __syncthreads();
        {
            const size_t ko = (size_t)t * 32;
            gl16(pA + ko,        dA);
            gl16(pA + a128 + ko, dA + 4096);
            gl16(pB + ko,        dB);
            gl16(pB + b128 + ko, dB + 4096);
        }
        __syncthreads();

        bf16x8 af[8], bfr[4];
#pragma unroll
        for (int i = 0; i < 8; ++i) af[i]  = *(const bf16x8*)(As + aoff + i * 512);
#pragma unroll
        for (int j = 0; j < 4; ++j) bfr[j] = *(const bf16x8*)(Bs + boff + j * 512);
        __builtin_amdgcn_s_setprio(1);
#pragma unroll
        for (int i = 0; i < 8; ++i)
#pragma unroll
            for (int j = 0; j < 4; ++j)
                acc[i][j] = __builtin_amdgcn_mfma_f32_16x16x32_bf16(af[i], bfr[j], acc[i][j], 0, 0, 0);
        __builtin_amdgcn_s_setprio(0);
    }

    // epilogue (verified R3/R5): acc[i][j][r] ->
    // C[m0+wave_m*128+i*16+quad*4+r][n0+wave_n*64+j*16+l15]
#pragma unroll
    for (int j = 0; j < 4; j++) {
        const int ncol = n0 + wave_n * 64 + j * 16 + l15;
        const float bb = b2f(bias[ncol]);
#pragma unroll
        for (int i = 0; i < 8; i++) {
            const int mbase = m0 + wave_m * 128 + i * 16 + quad * 4;
#pragma unroll
            for (int r = 0; r < 4; r++) {
                const int m = mbase + r;
                float v = acc[i][j][r] + bb;
                if (EPI == 0) {
                    ((u16*)outv)[(size_t)m * N + ncol] = f2bf(v);
                } else if (EPI == 1) {
                    float gg = 0.5f * v * (1.0f + erff(v * 0.70710678118654752f));
                    ((u16*)outv)[(size_t)m * N + ncol] = f2bf(gg);
                } else if (EPI == 2) {
                    size_t idx = (size_t)m * N + ncol;
                    float res = (sizeof(TRES) == 4) ? ((const float*)resid)[idx]
                                                    : b2f(((const u16*)resid)[idx]);
                    float o = v + res;
                    if (sizeof(TOUT) == 4) ((float*)outv)[idx] = o;
                    else                   ((u16*)outv)[idx]   = f2bf(o);
                } else {
                    int oc = (ncol < 768) ? ncol
                           : (ncol < 1536) ? (768 + ((ncol - 768) << 1))
                                           : (768 + ((ncol - 1536) << 1) + 1);
                    ((u16*)outv)[(size_t)m * 2304 + oc] = f2bf(v);
                }
            }
        }
    }
}

// ---------------------------------------------------------------------------
// LayerNorm over last dim (768). One block per row. Output bf16.
// ---------------------------------------------------------------------------
template <typename TIN>
__global__ __launch_bounds__(256) void layernorm_k(
    const void* __restrict__ xin,
    const u16* __restrict__ w,
    const u16* __restrict__ bb,
    u16* __restrict__ out)
{
    const int row = (int)blockIdx.x;
    const int tid = (int)threadIdx.x;
    float v[3];
    float s = 0.f, s2 = 0.f;
#pragma unroll
    for (int i = 0; i < 3; i++) {
        int c = tid + i * 256;
        float t = (sizeof(TIN) == 4) ? ((const float*)xin)[(size_t)row * C_ + c]
                                     : b2f(((const u16*)xin)[(size_t)row * C_ + c]);
        v[i] = t; s += t; s2 += t * t;
    }
#pragma unroll
    for (int o = 32; o > 0; o >>= 1) { s += __shfl_xor(s, o); s2 += __shfl_xor(s2, o); }
    __shared__ float red[8];
    const int wid = tid >> 6, lane = tid & 63;
    if (lane == 0) { red[wid] = s; red[4 + wid] = s2; }
    __syncthreads();
    s  = red[0] + red[1] + red[2] + red[3];
    s2 = red[4] + red[5] + red[6] + red[7];
    const float mean = s * (1.0f / C_);
    float var = s2 * (1.0f / C_) - mean * mean;
    const float rstd = rsqrtf(var + 1e-5f);
#pragma unroll
    for (int i = 0; i < 3; i++) {
        int c = tid + i * 256;
        float o_ = (v[i] - mean) * rstd * b2f(w[c]) + b2f(bb[c]);
        out[(size_t)row * C_ + c] = f2bf(o_);
    }
}

// ---------------------------------------------------------------------------
// Deformable sampling + attention v2. One wave per (b,h,n); lane = channel.
// ---------------------------------------------------------------------------
__global__ __launch_bounds__(256) void deform_attn(
    const u16* __restrict__ qkv,
    const u16* __restrict__ off,
    const float* __restrict__ refp,
    u16* __restrict__ out)
{
    const int tid  = (int)threadIdx.x;
    const int wid  = tid >> 6;
    const int lane = tid & 63;
    const int wav  = (int)blockIdx.x * 4 + wid;      // 0 .. B*N*HEADS-1
    const int h    = ui(wav % HEADS_);
    const int bn   = ui(wav / HEADS_);               // b*N + n
    const int b    = bn >> 12;

    const float qd = b2f(qkv[(size_t)bn * 2304 + h * HD_ + lane]);
    const float rx = uf(refp[(size_t)bn * 2 + 0]);
    const float ry = uf(refp[(size_t)bn * 2 + 1]);

    const u32* q32 = (const u32*)qkv;
    const int cidx = 384 + h * HD_ + lane;           // kv-interleaved u32 idx

    // ---- per-lane corner setup: t = lane&15, p = t>>2, c = t&3
    const int t4 = lane & 15;
    const int c  = t4 & 3;
    const uint4 ow = *(const uint4*)(off + (size_t)bn * 96 + h * 8);
    u32 owp = (t4 & 8) ? ((t4 & 4) ? ow.w : ow.z)
                       : ((t4 & 4) ? ow.y : ow.x);   // point p = t4>>2
    const float ox = b2f((u16)(owp & 0xffffu));
    const float oy = b2f((u16)(owp >> 16));
    float px = rx * (float)WW_ + ox - 0.5f;
    float py = ry * (float)HH_ + oy - 0.5f;
    px = fminf(fmaxf(px, -8.f), 72.f);               // NaN/garbage-proof
    py = fminf(fmaxf(py, -8.f), 72.f);
    const float x0f = floorf(px), y0f = floorf(py);
    const int   x0  = (int)x0f,   y0  = (int)y0f;
    const float wx  = px - x0f,   wy  = py - y0f;
    const int xi = x0 + (c & 1);
    const int yi = y0 + (c >> 1);
    const bool valid = ((u32)xi < (u32)WW_) & ((u32)yi < (u32)HH_);
    const int xc = min(max(xi, 0), WW_ - 1);
    const int yc = min(max(yi, 0), HH_ - 1);
    float wgt_c = ((c & 1) ? wx : 1.f - wx) * ((c & 2) ? wy : 1.f - wy);
    wgt_c = valid ? wgt_c : 0.f;
    const int base_c = ((b << 12) + yc * WW_ + xc) * 1152;

    // ---- broadcast 16 (base, wgt) to all lanes
    int   bt[16];
    float wgt[16];
#pragma unroll
    for (int t = 0; t < 16; t++) {
        bt[t]  = ui(__shfl(base_c, t));
        wgt[t] = uf(__shfl(wgt_c, t));
    }

    // ---- 16 independent gathers
    u32 kv[16];
#pragma unroll
    for (int t = 0; t < 16; t++) kv[t] = q32[(size_t)bt[t] + cidx];

    float logit[PTS_], svd[PTS_];
#pragma unroll
    for (int p = 0; p < PTS_; p++) {
        float sk = 0.f, sv = 0.f;
#pragma unroll
        for (int cc = 0; cc < 4; cc++) {
            const u32 x = kv[p * 4 + cc];
            const float w = wgt[p * 4 + cc];
            sk = fmaf(w, __int_as_float((int)(x << 16)), sk);
            sv = fmaf(w, __int_as_float((int)(x & 0xffff0000u)), sv);
        }
        logit[p] = qd * sk;
        svd[p]   = sv;
    }
#pragma unroll
    for (int p = 0; p < PTS_; p++)
#pragma unroll
        for (int o = 32; o > 0; o >>= 1) logit[p] += __shfl_xor(logit[p], o);

    const float scale = 0.125f;  // HD^-0.5
    float l0 = logit[0] * scale, l1 = logit[1] * scale, l2 = logit[2] * scale, l3 = logit[3] * scale;
    float mx = fmaxf(fmaxf(l0, l1), fmaxf(l2, l3));
    float e0 = __expf(l0 - mx), e1 = __expf(l1 - mx), e2 = __expf(l2 - mx), e3 = __expf(l3 - mx);
    float Z = e0 + e1 + e2 + e3;
    float od = (e0 * svd[0] + e1 * svd[1] + e2 * svd[2] + e3 * svd[3]) / Z;
    out[(size_t)bn * C_ + h * HD_ + lane] = f2bf(od);
}

// ---------------------------------------------------------------------------
extern "C" void kernel_launch(void* const* d_in, const int* in_sizes, int n_in,
                              void* d_out, int out_size, void* d_ws, size_t ws_size,
                              hipStream_t stream)
{
    const float* x     = (const float*)d_in[0];
    const float* refp  = (const float*)d_in[1];
    const float* n1w   = (const float*)d_in[2];
    const float* n1b   = (const float*)d_in[3];
    const float* qkvw  = (const float*)d_in[4];
    const float* qkvb  = (const float*)d_in[5];
    const float* offw  = (const float*)d_in[6];
    const float* offb  = (const float*)d_in[7];
    const float* projw = (const float*)d_in[8];
    const float* projb = (const float*)d_in[9];
    const float* n2w   = (const float*)d_in[10];
    const float* n2b   = (const float*)d_in[11];
    const float* fc1w  = (const float*)d_in[12];
    const float* fc1b  = (const float*)d_in[13];
    const float* fc2w  = (const float*)d_in[14];
    const float* fc2b  = (const float*)d_in[15];
    (void)in_sizes; (void)n_in; (void)out_size;

    const int M = B_ * N_;  // 16384

    const bool fullM = ws_size >= (size_t)168464064;

    char* ws = (char*)d_ws;
    u16* h    = (u16*)(ws);
    u16* aout = (u16*)(ws);
    u16* h2   = (u16*)(ws);
    u16* qkv  = (u16*)(ws + 25165824);
    u16* x1   = (u16*)(ws + 25165824);
    u16* mbuf = (u16*)(ws + 50331648);
    u16* offo = (u16*)(ws + (fullM ? 150994944 : 100663296));
    u16* cw   = (u16*)(ws + (fullM ? 154140672 : 103809024));

    u16* qkvw_c = cw +       0;
    u16* projw_c= cw + 1769472;
    u16* fc1w_c = cw + 2359296;
    u16* fc2w_c = cw + 4718592;
    u16* offw_c = cw + 7077888;
    u16* qkvb_c = cw + 7151616;
    u16* projb_c= cw + 7153920;
    u16* fc1b_c = cw + 7154688;
    u16* fc2b_c = cw + 7157760;
    u16* offb_c = cw + 7158528;
    u16* n1w_c  = cw + 7158624;
    u16* n1b_c  = cw + 7159392;
    u16* n2w_c  = cw + 7160160;
    u16* n2b_c  = cw + 7160928;

    dim3 blk(256);
    dim3 blk2(512);
    const int CH = 8192;                  // MLP row-chunk (chunked path)

    convert_k<<<dim3(2048), blk, 0, stream>>>(qkvw, projw, fc1w, fc2w, offw,
        qkvb, projb, fc1b, fc2b, offb, n1w, n1b, n2w, n2b, cw);
    // 1) LN1: x -> h
    layernorm_k<float><<<dim3(M), blk, 0, stream>>>(x, n1w_c, n1b_c, h);
    // 2) qkv = h @ qkv_w^T + qkv_b, kv interleaved (gemm1b)
    gemm1b<3, u16, u16><<<dim3((3 * C_) / 256, M / 256), blk2, 0, stream>>>(
        h, C_, qkvw_c, qkvb_c, nullptr, qkv, M, 3 * C_, C_);
    // 3) off = q @ off_w^T + off_b   (q = first 768 cols, lda=2304) (old gemm)
    gemm_nt<0, u16, u16><<<dim3(1, M / BM), blk, 0, stream>>>(
        qkv, 2304, offw_c, offb_c, nullptr, offo, M, HEADS_ * PTS_ * 2, C_);
    // 4) sampling + attention -> aout (h dead)
    deform_attn<<<dim3(M * HEADS_ / 4), blk, 0, stream>>>(qkv, offo, refp, aout);
    // 5) x1 = x + aout @ proj_w^T + proj_b (qkv dead -> x1) (gemm1b)
    gemm1b<2, float, u16><<<dim3(C_ / 256, M / 256), blk2, 0, stream>>>(
        aout, C_, projw_c, projb_c, x, x1, M, C_, C_);
    // 6) LN2: x1 -> h2 (aout dead)
    layernorm_k<u16><<<dim3(M), blk, 0, stream>>>(x1, n2w_c, n2b_c, h2);
    // 7/8) MLP (gemm1b)
    if (fullM) {
        gemm1b<1, u16, u16><<<dim3(HID_ / 256, M / 256), blk2, 0, stream>>>(
            h2, C_, fc1w_c, fc1b_c, nullptr, mbuf, M, HID_, C_);
        gemm1b<2, u16, float><<<dim3(C_ / 256, M / 256), blk2, 0, stream>>>(
            mbuf, HID_, fc2w_c, fc2b_c, x1, (float*)d_out, M, C_, HID_);
    } else {
        for (int c = 0; c < 2; c++) {
            const u16* h2c = h2 + (size_t)c * CH * C_;
            const u16* x1c = x1 + (size_t)c * CH * C_;
            float* outc = (float*)d_out + (size_t)c * CH * C_;
            gemm1b<1, u16, u16><<<dim3(HID_ / 256, CH / 256), blk2, 0, stream>>>(
                h2c, C_, fc1w_c, fc1b_c, nullptr, mbuf, CH, HID_, C_);
            gemm1b<2, u16, float><<<dim3(C_ / 256, CH / 256), blk2, 0, stream>>>(
                mbuf, HID_, fc2w_c, fc2b_c, x1c, outc, CH, C_, HID_);
        }
    }
}

// Round 7
// 669.158 us; speedup vs baseline: 1.1968x; 1.1968x over previous
//
#include <hip/hip_runtime.h>
#include <cstdint>
#include <cstddef>

// Problem constants. Inputs/outputs fp32 (confirmed R4).
#define B_     4
#define N_     4096
#define C_     768
#define HEADS_ 12
#define PTS_   4
#define HD_    64
#define HID_   3072
#define HH_    64
#define WW_    64

typedef unsigned short u16;
typedef unsigned int   u32;
typedef __bf16 bf16x8 __attribute__((ext_vector_type(8)));
typedef float  f32x4  __attribute__((ext_vector_type(4)));
typedef unsigned short ushort8 __attribute__((ext_vector_type(8)));

__device__ __forceinline__ float b2f(u16 x) {
    union { unsigned int u; float f; } v; v.u = ((unsigned int)x) << 16; return v.f;
}
__device__ __forceinline__ u16 f2bf(float f) {
    union { float f; unsigned int u; } v; v.f = f;
    unsigned int u = v.u;
    u = u + 0x7fffu + ((u >> 16) & 1u);   // RNE
    return (u16)(u >> 16);
}
__device__ __forceinline__ int   ui(int x)   { return __builtin_amdgcn_readfirstlane(x); }
__device__ __forceinline__ float uf(float x) { return __int_as_float(__builtin_amdgcn_readfirstlane(__float_as_int(x))); }

// async global->LDS, 16B/lane; LDS dst wave-uniform base, lane i -> base+i*16.
__device__ __forceinline__ void gl16(const u16* g, u16* l) {
    __builtin_amdgcn_global_load_lds((const __attribute__((address_space(1))) void*)g,
                                     (__attribute__((address_space(3))) void*)l, 16, 0, 0);
}

// ---------------------------------------------------------------------------
// fp32 weights/biases -> bf16 workspace.
// ---------------------------------------------------------------------------
__global__ __launch_bounds__(256) void convert_k(
    const float* qkvw, const float* projw, const float* fc1w, const float* fc2w,
    const float* offw, const float* qkvb, const float* projb, const float* fc1b,
    const float* fc2b, const float* offb, const float* n1w, const float* n1b,
    const float* n2w, const float* n2b,
    u16* __restrict__ dst)
{
    const int total = 7161696;
    for (int i = (int)blockIdx.x * 256 + (int)threadIdx.x; i < total; i += (int)gridDim.x * 256) {
        const float* src; int off;
        if      (i < 1769472) { src = qkvw;  off = i; }
        else if (i < 2359296) { src = projw; off = i - 1769472; }
        else if (i < 4718592) { src = fc1w;  off = i - 2359296; }
        else if (i < 7077888) { src = fc2w;  off = i - 4718592; }
        else if (i < 7151616) { src = offw;  off = i - 7077888; }
        else if (i < 7153920) { src = qkvb;  off = i - 7151616; }
        else if (i < 7154688) { src = projb; off = i - 7153920; }
        else if (i < 7157760) { src = fc1b;  off = i - 7154688; }
        else if (i < 7158528) { src = fc2b;  off = i - 7157760; }
        else if (i < 7158624) { src = offb;  off = i - 7158528; }
        else if (i < 7159392) { src = n1w;   off = i - 7158624; }
        else if (i < 7160160) { src = n1b;   off = i - 7159392; }
        else if (i < 7160928) { src = n2w;   off = i - 7160160; }
        else                  { src = n2b;   off = i - 7160928; }
        dst[i] = f2bf(src[off]);
    }
}

// ---------------------------------------------------------------------------
// OLD GEMM (128x128x64, 2-barrier). Kept for the tiny off-GEMM (N=96 row
// clamping).
// ---------------------------------------------------------------------------
#define BM 128
#define BN 128
#define BK 64

template <int EPI, typename TRES, typename TOUT>
__global__ __launch_bounds__(256) void gemm_nt(
    const u16* __restrict__ A, int lda,
    const u16* __restrict__ Bw,
    const u16* __restrict__ bias,
    const void* __restrict__ resid,
    void* __restrict__ outv,
    int M, int N, int K)
{
    __shared__ alignas(16) u16 As[BM * BK];   // 16 KB
    __shared__ alignas(16) u16 Bs[BN * BK];   // 16 KB

    const int tid  = (int)threadIdx.x;
    const int wid  = tid >> 6;
    const int lane = tid & 63;
    const int l15  = lane & 15;
    const int quad = lane >> 4;
    const int m0   = (int)blockIdx.y * BM;
    const int n0   = (int)blockIdx.x * BN;
    const int wm   = (wid & 1) * 64;
    const int wn   = (wid >> 1) * 64;

    const f32x4 zero4 = {0.f, 0.f, 0.f, 0.f};
    f32x4 acc[4][4];
#pragma unroll
    for (int i = 0; i < 4; i++)
#pragma unroll
        for (int j = 0; j < 4; j++) acc[i][j] = zero4;

    const int srow = tid >> 3;                         // 0..31
    const int scol = (((tid & 7) ^ (srow & 7))) * 8;   // swizzled source col (u16)
    const u16* pa = A + (size_t)(m0 + srow) * lda + scol;
    int brow[4];
#pragma unroll
    for (int q = 0; q < 4; q++) {
        int r = n0 + srow + q * 32;
        brow[q] = (r > N - 1) ? (N - 1) : r;
    }

    const int swz = l15 & 7;  // fragment-row & 7, lane-constant

    for (int k0 = 0; k0 < K; k0 += BK) {
        __syncthreads();
#pragma unroll
        for (int q = 0; q < 4; q++) {
            gl16(pa + (size_t)(q * 32) * lda + k0, As + (size_t)(q * 256 + wid * 64) * 8);
            gl16(Bw + (size_t)brow[q] * K + scol + k0, Bs + (size_t)(q * 256 + wid * 64) * 8);
        }
        __syncthreads();

#pragma unroll
        for (int half = 0; half < 2; half++) {
            bf16x8 af[4], bfr[4];
#pragma unroll
            for (int i = 0; i < 4; i++)
                af[i] = *(const bf16x8*)(As + (wm + i * 16 + l15) * BK + (((half * 4 + quad) ^ swz) * 8));
#pragma unroll
            for (int j = 0; j < 4; j++)
                bfr[j] = *(const bf16x8*)(Bs + (wn + j * 16 + l15) * BK + (((half * 4 + quad) ^ swz) * 8));
#pragma unroll
            for (int i = 0; i < 4; i++)
#pragma unroll
                for (int j = 0; j < 4; j++)
                    acc[i][j] = __builtin_amdgcn_mfma_f32_16x16x32_bf16(af[i], bfr[j], acc[i][j], 0, 0, 0);
        }
    }

#pragma unroll
    for (int j = 0; j < 4; j++) {
        int ncol = n0 + wn + j * 16 + l15;
        if (ncol >= N) continue;
        float bb = b2f(bias[ncol]);
#pragma unroll
        for (int i = 0; i < 4; i++) {
            int mbase = m0 + wm + i * 16 + quad * 4;
#pragma unroll
            for (int r = 0; r < 4; r++) {
                int m = mbase + r;
                float v = acc[i][j][r] + bb;
                if (EPI == 0) {
                    ((u16*)outv)[(size_t)m * N + ncol] = f2bf(v);
                } else if (EPI == 1) {
                    float g = 0.5f * v * (1.0f + erff(v * 0.70710678118654752f));
                    ((u16*)outv)[(size_t)m * N + ncol] = f2bf(g);
                } else if (EPI == 2) {
                    size_t idx = (size_t)m * N + ncol;
                    float res = (sizeof(TRES) == 4) ? ((const float*)resid)[idx]
                                                    : b2f(((const u16*)resid)[idx]);
                    float o = v + res;
                    if (sizeof(TOUT) == 4) ((float*)outv)[idx] = o;
                    else                   ((u16*)outv)[idx]   = f2bf(o);
                } else {
                    int oc = (ncol < 768) ? ncol
                           : (ncol < 1536) ? (768 + ((ncol - 768) << 1))
                                           : (768 + ((ncol - 1536) << 1) + 1);
                    ((u16*)outv)[(size_t)m * 2304 + oc] = f2bf(v);
                }
            }
        }
    }
}

// ---------------------------------------------------------------------------
// gemm2p v2: 128x128x64 tile, 256 thr (4 waves), double-buffered LDS (64 KB
// -> 2 blocks/CU).  KEY FIX vs R4: ALL 16 fragment ds_reads complete BEFORE
// any gl16 of tile t+1 is issued.  The compiler cannot disambiguate
// As[cur] (read) from As[cur^1] (gl16 dst) and inserts a conservative
// vmcnt(0) before LDS reads that follow a gl16 — which was draining the
// prefetch queue every step (measured ~6.5 B/cyc/CU staging across ALL
// schedule variants).  With reads first, the only read-after-gl16 point is
// the loop-top (next iter), where our manual vmcnt(0) already sits -> any
// compiler wait there is free, and the 8 staging loads of t+1 fly under
// the 32 MFMA + the co-resident block.
// Order per iter: [read af0/af1/bf0/bf1] SB [stage t+1] SB [32 MFMA prio]
// [vmcnt(0)] [s_barrier].  Race-free: stage(t+1) writes buf^1, last read
// of buf^1 was iter t-1 before its closing barrier.
// Requires M%128==0, N%128==0, K%64==0.
// ---------------------------------------------------------------------------
template <int EPI, typename TRES, typename TOUT>
__global__ __launch_bounds__(256) void gemm2p(
    const u16* __restrict__ A, int lda,
    const u16* __restrict__ Bw,
    const u16* __restrict__ bias,
    const void* __restrict__ resid,
    void* __restrict__ outv,
    int M, int N, int K)
{
    __shared__ alignas(16) u16 As[2][BM * BK];   // 2 x 16 KB
    __shared__ alignas(16) u16 Bs[2][BN * BK];   // 2 x 16 KB

    const int tid  = (int)threadIdx.x;
    const int wid  = tid >> 6;
    const int lane = tid & 63;
    const int l15  = lane & 15;
    const int quad = lane >> 4;
    const int m0   = (int)blockIdx.y * BM;
    const int n0   = (int)blockIdx.x * BN;
    const int wm   = (wid & 1) * 64;
    const int wn   = (wid >> 1) * 64;

    const f32x4 zero4 = {0.f, 0.f, 0.f, 0.f};
    f32x4 acc[4][4];
#pragma unroll
    for (int i = 0; i < 4; i++)
#pragma unroll
        for (int j = 0; j < 4; j++) acc[i][j] = zero4;

    const int srow = tid >> 3;                         // 0..31
    const int scol = (((tid & 7) ^ (srow & 7))) * 8;   // swizzled source col (u16)
    const u16* pa = A + (size_t)(m0 + srow) * lda + scol;
    const u16* pb = Bw + (size_t)(n0 + srow) * K + scol;
    const int swz = l15 & 7;
    const int nt  = K / BK;

#define STAGE2(t, bf) do {                                                          \
        _Pragma("unroll")                                                           \
        for (int q = 0; q < 4; q++) {                                               \
            gl16(pa + (size_t)(q * 32) * lda + (size_t)(t) * BK,                    \
                 &As[bf][0] + (size_t)(q * 256 + wid * 64) * 8);                    \
            gl16(pb + (size_t)(q * 32) * K + (size_t)(t) * BK,                      \
                 &Bs[bf][0] + (size_t)(q * 256 + wid * 64) * 8);                    \
        }                                                                           \
    } while (0)

    // prologue: stage tile 0, drain, barrier
    STAGE2(0, 0);
    asm volatile("s_waitcnt vmcnt(0)" ::: "memory");
    __builtin_amdgcn_s_barrier();
    __builtin_amdgcn_sched_barrier(0);

    for (int t = 0; t < nt; ++t) {
        const int cur = t & 1;
        const u16* Ab = &As[cur][0];
        const u16* Bb = &Bs[cur][0];

        // ---- ALL fragment reads first (no gl16 issued yet this iter)
        bf16x8 af0[4], bf0[4], af1[4], bf1[4];
#pragma unroll
        for (int i = 0; i < 4; i++) {
            af0[i] = *(const bf16x8*)(Ab + (wm + i * 16 + l15) * BK + (((0 + quad) ^ swz) * 8));
            af1[i] = *(const bf16x8*)(Ab + (wm + i * 16 + l15) * BK + (((4 + quad) ^ swz) * 8));
        }
#pragma unroll
        for (int j = 0; j < 4; j++) {
            bf0[j] = *(const bf16x8*)(Bb + (wn + j * 16 + l15) * BK + (((0 + quad) ^ swz) * 8));
            bf1[j] = *(const bf16x8*)(Bb + (wn + j * 16 + l15) * BK + (((4 + quad) ^ swz) * 8));
        }
        __builtin_amdgcn_sched_barrier(0);

        // ---- issue next tile's staging (flies under the MFMA below)
        if (t + 1 < nt) STAGE2(t + 1, cur ^ 1);
        __builtin_amdgcn_sched_barrier(0);

        // ---- 32 MFMA
        __builtin_amdgcn_s_setprio(1);
#pragma unroll
        for (int i = 0; i < 4; i++)
#pragma unroll
            for (int j = 0; j < 4; j++)
                acc[i][j] = __builtin_amdgcn_mfma_f32_16x16x32_bf16(af0[i], bf0[j], acc[i][j], 0, 0, 0);
#pragma unroll
        for (int i = 0; i < 4; i++)
#pragma unroll
            for (int j = 0; j < 4; j++)
                acc[i][j] = __builtin_amdgcn_mfma_f32_16x16x32_bf16(af1[i], bf1[j], acc[i][j], 0, 0, 0);
        __builtin_amdgcn_s_setprio(0);

        asm volatile("s_waitcnt vmcnt(0)" ::: "memory");
        __builtin_amdgcn_s_barrier();
        __builtin_amdgcn_sched_barrier(0);
    }
#undef STAGE2

#pragma unroll
    for (int j = 0; j < 4; j++) {
        int ncol = n0 + wn + j * 16 + l15;
        float bb = b2f(bias[ncol]);
#pragma unroll
        for (int i = 0; i < 4; i++) {
            int mbase = m0 + wm + i * 16 + quad * 4;
#pragma unroll
            for (int r = 0; r < 4; r++) {
                int m = mbase + r;
                float v = acc[i][j][r] + bb;
                if (EPI == 0) {
                    ((u16*)outv)[(size_t)m * N + ncol] = f2bf(v);
                } else if (EPI == 1) {
                    float g = 0.5f * v * (1.0f + erff(v * 0.70710678118654752f));
                    ((u16*)outv)[(size_t)m * N + ncol] = f2bf(g);
                } else if (EPI == 2) {
                    size_t idx = (size_t)m * N + ncol;
                    float res = (sizeof(TRES) == 4) ? ((const float*)resid)[idx]
                                                    : b2f(((const u16*)resid)[idx]);
                    float o = v + res;
                    if (sizeof(TOUT) == 4) ((float*)outv)[idx] = o;
                    else                   ((u16*)outv)[idx]   = f2bf(o);
                } else {
                    int oc = (ncol < 768) ? ncol
                           : (ncol < 1536) ? (768 + ((ncol - 768) << 1))
                                           : (768 + ((ncol - 1536) << 1) + 1);
                    ((u16*)outv)[(size_t)m * 2304 + oc] = f2bf(v);
                }
            }
        }
    }
}

// ---------------------------------------------------------------------------
// LayerNorm over last dim (768). One block per row. Output bf16.
// ---------------------------------------------------------------------------
template <typename TIN>
__global__ __launch_bounds__(256) void layernorm_k(
    const void* __restrict__ xin,
    const u16* __restrict__ w,
    const u16* __restrict__ bb,
    u16* __restrict__ out)
{
    const int row = (int)blockIdx.x;
    const int tid = (int)threadIdx.x;
    float v[3];
    float s = 0.f, s2 = 0.f;
#pragma unroll
    for (int i = 0; i < 3; i++) {
        int c = tid + i * 256;
        float t = (sizeof(TIN) == 4) ? ((const float*)xin)[(size_t)row * C_ + c]
                                     : b2f(((const u16*)xin)[(size_t)row * C_ + c]);
        v[i] = t; s += t; s2 += t * t;
    }
#pragma unroll
    for (int o = 32; o > 0; o >>= 1) { s += __shfl_xor(s, o); s2 += __shfl_xor(s2, o); }
    __shared__ float red[8];
    const int wid = tid >> 6, lane = tid & 63;
    if (lane == 0) { red[wid] = s; red[4 + wid] = s2; }
    __syncthreads();
    s  = red[0] + red[1] + red[2] + red[3];
    s2 = red[4] + red[5] + red[6] + red[7];
    const float mean = s * (1.0f / C_);
    float var = s2 * (1.0f / C_) - mean * mean;
    const float rstd = rsqrtf(var + 1e-5f);
#pragma unroll
    for (int i = 0; i < 3; i++) {
        int c = tid + i * 256;
        float o_ = (v[i] - mean) * rstd * b2f(w[c]) + b2f(bb[c]);
        out[(size_t)row * C_ + c] = f2bf(o_);
    }
}

// ---------------------------------------------------------------------------
// Deformable sampling + attention v2. One wave per (b,h,n); lane = channel.
// ---------------------------------------------------------------------------
__global__ __launch_bounds__(256) void deform_attn(
    const u16* __restrict__ qkv,
    const u16* __restrict__ off,
    const float* __restrict__ refp,
    u16* __restrict__ out)
{
    const int tid  = (int)threadIdx.x;
    const int wid  = tid >> 6;
    const int lane = tid & 63;
    const int wav  = (int)blockIdx.x * 4 + wid;      // 0 .. B*N*HEADS-1
    const int h    = ui(wav % HEADS_);
    const int bn   = ui(wav / HEADS_);               // b*N + n
    const int b    = bn >> 12;

    const float qd = b2f(qkv[(size_t)bn * 2304 + h * HD_ + lane]);
    const float rx = uf(refp[(size_t)bn * 2 + 0]);
    const float ry = uf(refp[(size_t)bn * 2 + 1]);

    const u32* q32 = (const u32*)qkv;
    const int cidx = 384 + h * HD_ + lane;           // kv-interleaved u32 idx

    // ---- per-lane corner setup: t = lane&15, p = t>>2, c = t&3
    const int t4 = lane & 15;
    const int c  = t4 & 3;
    const uint4 ow = *(const uint4*)(off + (size_t)bn * 96 + h * 8);
    u32 owp = (t4 & 8) ? ((t4 & 4) ? ow.w : ow.z)
                       : ((t4 & 4) ? ow.y : ow.x);   // point p = t4>>2
    const float ox = b2f((u16)(owp & 0xffffu));
    const float oy = b2f((u16)(owp >> 16));
    float px = rx * (float)WW_ + ox - 0.5f;
    float py = ry * (float)HH_ + oy - 0.5f;
    px = fminf(fmaxf(px, -8.f), 72.f);               // NaN/garbage-proof
    py = fminf(fmaxf(py, -8.f), 72.f);
    const float x0f = floorf(px), y0f = floorf(py);
    const int   x0  = (int)x0f,   y0  = (int)y0f;
    const float wx  = px - x0f,   wy  = py - y0f;
    const int xi = x0 + (c & 1);
    const int yi = y0 + (c >> 1);
    const bool valid = ((u32)xi < (u32)WW_) & ((u32)yi < (u32)HH_);
    const int xc = min(max(xi, 0), WW_ - 1);
    const int yc = min(max(yi, 0), HH_ - 1);
    float wgt_c = ((c & 1) ? wx : 1.f - wx) * ((c & 2) ? wy : 1.f - wy);
    wgt_c = valid ? wgt_c : 0.f;
    const int base_c = ((b << 12) + yc * WW_ + xc) * 1152;

    // ---- broadcast 16 (base, wgt) to all lanes
    int   bt[16];
    float wgt[16];
#pragma unroll
    for (int t = 0; t < 16; t++) {
        bt[t]  = ui(__shfl(base_c, t));
        wgt[t] = uf(__shfl(wgt_c, t));
    }

    // ---- 16 independent gathers
    u32 kv[16];
#pragma unroll
    for (int t = 0; t < 16; t++) kv[t] = q32[(size_t)bt[t] + cidx];

    float logit[PTS_], svd[PTS_];
#pragma unroll
    for (int p = 0; p < PTS_; p++) {
        float sk = 0.f, sv = 0.f;
#pragma unroll
        for (int cc = 0; cc < 4; cc++) {
            const u32 x = kv[p * 4 + cc];
            const float w = wgt[p * 4 + cc];
            sk = fmaf(w, __int_as_float((int)(x << 16)), sk);
            sv = fmaf(w, __int_as_float((int)(x & 0xffff0000u)), sv);
        }
        logit[p] = qd * sk;
        svd[p]   = sv;
    }
#pragma unroll
    for (int p = 0; p < PTS_; p++)
#pragma unroll
        for (int o = 32; o > 0; o >>= 1) logit[p] += __shfl_xor(logit[p], o);

    const float scale = 0.125f;  // HD^-0.5
    float l0 = logit[0] * scale, l1 = logit[1] * scale, l2 = logit[2] * scale, l3 = logit[3] * scale;
    float mx = fmaxf(fmaxf(l0, l1), fmaxf(l2, l3));
    float e0 = __expf(l0 - mx), e1 = __expf(l1 - mx), e2 = __expf(l2 - mx), e3 = __expf(l3 - mx);
    float Z = e0 + e1 + e2 + e3;
    float od = (e0 * svd[0] + e1 * svd[1] + e2 * svd[2] + e3 * svd[3]) / Z;
    out[(size_t)bn * C_ + h * HD_ + lane] = f2bf(od);
}

// ---------------------------------------------------------------------------
extern "C" void kernel_launch(void* const* d_in, const int* in_sizes, int n_in,
                              void* d_out, int out_size, void* d_ws, size_t ws_size,
                              hipStream_t stream)
{
    const float* x     = (const float*)d_in[0];
    const float* refp  = (const float*)d_in[1];
    const float* n1w   = (const float*)d_in[2];
    const float* n1b   = (const float*)d_in[3];
    const float* qkvw  = (const float*)d_in[4];
    const float* qkvb  = (const float*)d_in[5];
    const float* offw  = (const float*)d_in[6];
    const float* offb  = (const float*)d_in[7];
    const float* projw = (const float*)d_in[8];
    const float* projb = (const float*)d_in[9];
    const float* n2w   = (const float*)d_in[10];
    const float* n2b   = (const float*)d_in[11];
    const float* fc1w  = (const float*)d_in[12];
    const float* fc1b  = (const float*)d_in[13];
    const float* fc2w  = (const float*)d_in[14];
    const float* fc2b  = (const float*)d_in[15];
    (void)in_sizes; (void)n_in; (void)out_size;

    const int M = B_ * N_;  // 16384

    const bool fullM = ws_size >= (size_t)168464064;

    char* ws = (char*)d_ws;
    u16* h    = (u16*)(ws);
    u16* aout = (u16*)(ws);
    u16* h2   = (u16*)(ws);
    u16* qkv  = (u16*)(ws + 25165824);
    u16* x1   = (u16*)(ws + 25165824);
    u16* mbuf = (u16*)(ws + 50331648);
    u16* offo = (u16*)(ws + (fullM ? 150994944 : 100663296));
    u16* cw   = (u16*)(ws + (fullM ? 154140672 : 103809024));

    u16* qkvw_c = cw +       0;
    u16* projw_c= cw + 1769472;
    u16* fc1w_c = cw + 2359296;
    u16* fc2w_c = cw + 4718592;
    u16* offw_c = cw + 7077888;
    u16* qkvb_c = cw + 7151616;
    u16* projb_c= cw + 7153920;
    u16* fc1b_c = cw + 7154688;
    u16* fc2b_c = cw + 7157760;
    u16* offb_c = cw + 7158528;
    u16* n1w_c  = cw + 7158624;
    u16* n1b_c  = cw + 7159392;
    u16* n2w_c  = cw + 7160160;
    u16* n2b_c  = cw + 7160928;

    dim3 blk(256);
    const int CH = 8192;                  // MLP row-chunk (chunked path)

    convert_k<<<dim3(2048), blk, 0, stream>>>(qkvw, projw, fc1w, fc2w, offw,
        qkvb, projb, fc1b, fc2b, offb, n1w, n1b, n2w, n2b, cw);
    // 1) LN1: x -> h
    layernorm_k<float><<<dim3(M), blk, 0, stream>>>(x, n1w_c, n1b_c, h);
    // 2) qkv = h @ qkv_w^T + qkv_b, kv interleaved (gemm2p v2)
    gemm2p<3, u16, u16><<<dim3((3 * C_) / BN, M / BM), blk, 0, stream>>>(
        h, C_, qkvw_c, qkvb_c, nullptr, qkv, M, 3 * C_, C_);
    // 3) off = q @ off_w^T + off_b   (q = first 768 cols, lda=2304) (old gemm)
    gemm_nt<0, u16, u16><<<dim3(1, M / BM), blk, 0, stream>>>(
        qkv, 2304, offw_c, offb_c, nullptr, offo, M, HEADS_ * PTS_ * 2, C_);
    // 4) sampling + attention -> aout (h dead)
    deform_attn<<<dim3(M * HEADS_ / 4), blk, 0, stream>>>(qkv, offo, refp, aout);
    // 5) x1 = x + aout @ proj_w^T + proj_b (qkv dead -> x1) (gemm2p v2)
    gemm2p<2, float, u16><<<dim3(C_ / BN, M / BM), blk, 0, stream>>>(
        aout, C_, projw_c, projb_c, x, x1, M, C_, C_);
    // 6) LN2: x1 -> h2 (aout dead)
    layernorm_k<u16><<<dim3(M), blk, 0, stream>>>(x1, n2w_c, n2b_c, h2);
    // 7/8) MLP (gemm2p v2)
    if (fullM) {
        gemm2p<1, u16, u16><<<dim3(HID_ / BN, M / BM), blk, 0, stream>>>(
            h2, C_, fc1w_c, fc1b_c, nullptr, mbuf, M, HID_, C_);
        gemm2p<2, u16, float><<<dim3(C_ / BN, M / BM), blk, 0, stream>>>(
            mbuf, HID_, fc2w_c, fc2b_c, x1, (float*)d_out, M, C_, HID_);
    } else {
        for (int c = 0; c < 2; c++) {
            const u16* h2c = h2 + (size_t)c * CH * C_;
            const u16* x1c = x1 + (size_t)c * CH * C_;
            float* outc = (float*)d_out + (size_t)c * CH * C_;
            gemm2p<1, u16, u16><<<dim3(HID_ / BN, CH / BM), blk, 0, stream>>>(
                h2c, C_, fc1w_c, fc1b_c, nullptr, mbuf, CH, HID_, C_);
            gemm2p<2, u16, float><<<dim3(C_ / BN, CH / BM), blk, 0, stream>>>(
                mbuf, HID_, fc2w_c, fc2b_c, x1c, outc, CH, C_, HID_);
        }
    }
}